// Round 5
// baseline (31.026 us; speedup 1.0000x reference)
//
#include <hip/hip_runtime.h>
#include <hip/hip_bf16.h>

// Volterra conv (K=3, orders 1+2) as one fused bf16 MFMA GEMM:
// out[b, l, o] = sum_{c,f} A[l, c*64+f] * Wc[c*64+f, o]
//   f<9: linear xp[f]; 9<=f<54: xp[P]*xp[Q]/sqrt(45) (scale folded into Bpack); f>=54: 0
// Flat out = b*262144 + h_pix*4096 + w_pix*64 + o  (== ref out[b,o_ch=h_pix,h=w_pix,w=o]),
// bias = bias_w[h_pix] (zeros in practice). Verified passing in r2-r4.
//
// volt_main r5: grid 512 = (b, h, whalf); 512 thr = 8 waves, K-split 8 ch/wave.
// Each wave: 32 pixels x 64 out-cols. lane=(kh<<5)|p matches MFMA A layout ->
// A-frags built lane-local (no half-exchange). B loaded register-direct JIT from
// Bpack (per-lane frag order, coalesced uint4, L2-resident). LDS (64KB) only for
// the final 8-way cross-wave K reduction -> 2 wgs/CU, 4 waves/SIMD.

typedef __bf16 bf16x8 __attribute__((ext_vector_type(8)));
typedef float f32x16 __attribute__((ext_vector_type(16)));

#define SCALE_Q 0.14907119849998599f  // 1/sqrt(45)

__device__ __constant__ int g_pairP[45] = {
  0,0,0,0,0,0,0,0,0, 1,1,1,1,1,1,1,1, 2,2,2,2,2,2,2,
  3,3,3,3,3,3, 4,4,4,4,4, 5,5,5,5, 6,6,6, 7,7, 8};
__device__ __constant__ int g_pairQ[45] = {
  0,1,2,3,4,5,6,7,8, 1,2,3,4,5,6,7,8, 2,3,4,5,6,7,8,
  3,4,5,6,7,8, 4,5,6,7,8, 5,6,7,8, 6,7,8, 7,8, 8};

// compile-time pair tables for slot values
constexpr int cP[45] = {
  0,0,0,0,0,0,0,0,0, 1,1,1,1,1,1,1,1, 2,2,2,2,2,2,2,
  3,3,3,3,3,3, 4,4,4,4,4, 5,5,5,5, 6,6,6, 7,7, 8};
constexpr int cQ[45] = {
  0,1,2,3,4,5,6,7,8, 1,2,3,4,5,6,7,8, 2,3,4,5,6,7,8,
  3,4,5,6,7,8, 4,5,6,7,8, 5,6,7,8, 6,7,8, 7,8, 8};

union AFrag { unsigned int u[4]; bf16x8 v; };
union BFrag { uint4 q; bf16x8 v; };

__device__ inline unsigned int pack_bf16x2(float a, float b){
  union { __hip_bfloat16 h; unsigned short s; } ca, cb;
  ca.h = __float2bfloat16(a);
  cb.h = __float2bfloat16(b);
  return (unsigned int)ca.s | ((unsigned int)cb.s << 16);
}

template<int F>
__device__ inline float slotval(const float (&xp)[9]){
  if constexpr (F < 9)       return xp[F];
  else if constexpr (F < 54) return xp[cP[F - 9]] * xp[cQ[F - 9]];
  else                       return 0.0f;
}

// Build this lane's A fragments for its k-half KH: frag element e of kstep ks is
// feature slot f = ks*16 + KH*8 + e  (dword j holds e=2j,2j+1).
template<int KH>
__device__ inline void build_afrag(const float (&xp)[9], AFrag (&a)[4]){
  #pragma unroll
  for (int ks = 0; ks < 4; ++ks){
    #pragma unroll
    for (int j = 0; j < 4; ++j){
      constexpr int base = 0;  (void)base;
      const int f0c = ks * 16 + KH * 8 + 2 * j;   // constant after unroll
      float v0, v1;
      switch (f0c) {  // force compile-time dispatch of both slot values
        default: v0 = 0.f; v1 = 0.f; break;
  #define CASE(F) case F: v0 = slotval<F>(xp); v1 = slotval<F+1>(xp); break;
        CASE(0) CASE(2) CASE(4) CASE(6) CASE(8) CASE(10) CASE(12) CASE(14)
        CASE(16) CASE(18) CASE(20) CASE(22) CASE(24) CASE(26) CASE(28) CASE(30)
        CASE(32) CASE(34) CASE(36) CASE(38) CASE(40) CASE(42) CASE(44) CASE(46)
        CASE(48) CASE(50) CASE(52) CASE(54) CASE(56) CASE(58) CASE(60) CASE(62)
  #undef CASE
      }
      a[ks].u[j] = pack_bf16x2(v0, v1);
    }
  }
}

// ---------------- prep: pack weights into MFMA B-fragment order ----------------
// chunk g in [0,32768): c=g>>9; inner=g&511 = (ks*2+nb)*64 + lane.
// chunk (8 bf16) = B[k-slot = ks*16 + (lane>>5)*8 + j][n = nb*32 + (lane&31)]
__global__ __launch_bounds__(256) void volt_pack(const float* __restrict__ W1,
                                                 const float* __restrict__ W2,
                                                 __hip_bfloat16* __restrict__ Bpack){
  int g = blockIdx.x * 256 + threadIdx.x;      // 0..32767
  int c     = g >> 9;
  int inner = g & 511;
  int lane  = inner & 63;
  int ks    = inner >> 7;
  int nb    = (inner >> 6) & 1;
  int n     = nb * 32 + (lane & 31);
  int kh    = lane >> 5;
  #pragma unroll
  for (int j = 0; j < 8; ++j){
    int f = ks * 16 + kh * 8 + j;              // feature slot within channel
    float wv = 0.0f;
    if (f < 9)       wv = W1[(c * 9 + f) * 64 + n];
    else if (f < 54){
      int t = f - 9;
      wv = SCALE_Q * W2[(c * 81 + g_pairP[t] * 9 + g_pairQ[t]) * 64 + n];
    }
    Bpack[(size_t)g * 8 + j] = __float2bfloat16(wv);
  }
}

// ---------------- main fused kernel ----------------
__global__ __launch_bounds__(512, 4) void volt_main(const float* __restrict__ x,
                                                    const uint4* __restrict__ Bpack,
                                                    const float* __restrict__ bias_w,
                                                    float* __restrict__ out){
  __shared__ float red[8 * 2048];              // 64 KB: per-wave partial 32x64 C tiles
  const int tid   = threadIdx.x;
  const int lane  = tid & 63;
  const int kv    = tid >> 6;                  // wave 0..7, channels kv*8..kv*8+7
  const int bid   = blockIdx.x;
  const int b     = bid >> 7;
  const int h0    = (bid >> 1) & 63;
  const int whalf = bid & 1;
  const int wstart = whalf << 5;

  const int p  = lane & 31;                    // pixel within half-row
  const int kh = lane >> 5;                    // k-half

  const int hm = (h0 > 0)  ? h0 - 1 : 0;
  const int hp = (h0 < 63) ? h0 + 1 : 63;

  const float* xw  = x + ((size_t)(b * 64 + kv * 8)) * 4096;
  const uint4* bsrc = Bpack + (size_t)(kv * 8) * 512 + lane;

  // halo column loader: lanes 0..33 cover cols wstart-1 .. wstart+32 (OOB -> 0)
  const int col  = wstart - 1 + lane;
  const bool cok = (lane < 34) && ((unsigned)col < 64u);

  auto loadX = [&](int i, float (&v)[3]){
    const float* xc = xw + (size_t)i * 4096;
    v[0] = cok ? xc[hm * 64 + col] : 0.f;
    v[1] = cok ? xc[h0 * 64 + col] : 0.f;
    v[2] = cok ? xc[hp * 64 + col] : 0.f;
    if (h0 == 0)  v[0] = 0.f;                  // wave-uniform row clamp
    if (h0 == 63) v[2] = 0.f;
  };

  f32x16 acc0{}, acc1{};                       // cols 0..31 / 32..63
  float cx[3];
  loadX(0, cx);

  #pragma unroll
  for (int i = 0; i < 8; ++i){
    // JIT B fragments for this channel (coalesced, L2-resident)
    BFrag Bf[8];
    const uint4* s = bsrc + (size_t)i * 512;
    #pragma unroll
    for (int j = 0; j < 8; ++j) Bf[j].q = s[j * 64];

    float nx2[3];
    if (i < 7) loadX(i + 1, nx2);              // x prefetch (3 regs)

    // ---- xp[9] for this lane's pixel (w = wstart + p), from halo via shfl ----
    float xp[9];
    #pragma unroll
    for (int dh = 0; dh < 3; ++dh){
      float hv = cx[dh];
      xp[dh * 3 + 0] = __shfl(hv, p);          // col w-1
      xp[dh * 3 + 1] = __shfl(hv, p + 1);      // col w
      xp[dh * 3 + 2] = __shfl(hv, p + 2);      // col w+1
    }

    // ---- lane-local A fragments (k-half split; no cross-lane exchange) ----
    AFrag a[4];
    if (kh == 0) build_afrag<0>(xp, a);
    else         build_afrag<1>(xp, a);

    // ---- MFMA: 4 ksteps x 2 col-halves ----
    __builtin_amdgcn_s_setprio(1);
    #pragma unroll
    for (int ks = 0; ks < 4; ++ks){
      acc0 = __builtin_amdgcn_mfma_f32_32x32x16_bf16(a[ks].v, Bf[ks*2+0].v, acc0, 0, 0, 0);
      acc1 = __builtin_amdgcn_mfma_f32_32x32x16_bf16(a[ks].v, Bf[ks*2+1].v, acc1, 0, 0, 0);
    }
    __builtin_amdgcn_s_setprio(0);

    if (i < 7){ cx[0] = nx2[0]; cx[1] = nx2[1]; cx[2] = nx2[2]; }
  }

  // ---- cross-wave K reduction via LDS ----
  {
    #pragma unroll
    for (int r = 0; r < 16; ++r){
      int rl = (r & 3) + 8 * (r >> 2) + 4 * kh;            // 32x32 C/D row
      red[kv * 2048 + rl * 64 + p     ] = acc0[r];
      red[kv * 2048 + rl * 64 + p + 32] = acc1[r];
    }
  }
  __syncthreads();
  const float bias = bias_w[h0];
  float* outp = out + (size_t)b * 262144 + (size_t)h0 * 4096 + (size_t)wstart * 64;
  #pragma unroll
  for (int j = 0; j < 4; ++j){
    int oidx = j * 512 + tid;                  // (local pixel)*64 + o, coalesced
    float v = bias;
    #pragma unroll
    for (int kvv = 0; kvv < 8; ++kvv) v += red[kvv * 2048 + oidx];
    outp[oidx] = v;
  }
}

extern "C" void kernel_launch(void* const* d_in, const int* in_sizes, int n_in,
                              void* d_out, int out_size, void* d_ws, size_t ws_size,
                              hipStream_t stream){
  const float* x      = (const float*)d_in[0];
  const float* W1     = (const float*)d_in[1];
  const float* W2     = (const float*)d_in[2];
  const float* bias_w = (const float*)d_in[3];
  float* out = (float*)d_out;
  __hip_bfloat16* Bpack = (__hip_bfloat16*)d_ws;   // 512 KB

  volt_pack<<<128, 256, 0, stream>>>(W1, W2, Bpack);
  volt_main<<<512, 512, 0, stream>>>(x, (const uint4*)d_ws, bias_w, out);
}

// Round 6
// 26.565 us; speedup vs baseline: 1.1679x; 1.1679x over previous
//
#include <hip/hip_runtime.h>
#include <hip/hip_bf16.h>

// Volterra conv (K=3, orders 1+2) as one fused bf16 MFMA GEMM:
// out[b, l, o] = sum_{c,f} A[l, c*64+f] * Wc[c*64+f, o]
//   f<9: linear xp[f]; 9<=f<54: xp[P]*xp[Q]/sqrt(45) (scale folded into Bpack); f>=54: 0
// Flat out = b*262144 + h_pix*4096 + w_pix*64 + o; bias = bias_w[h_pix] (zeros).
//
// r6: grid 256 = (b,h) -> 1 wg/CU; 512 thr = 8 waves, K-split 8 ch/wave.
// lane = (kh<<5)|p. Each lane builds A-frags lane-locally (no cross-lane exchange)
// for TWO pixels (p and p+32), so each register-resident B frag feeds 4 independent
// MFMA chains (2 px-tiles x 2 col-halves). B double-buffered in regs (prefetch one
// channel ahead). LDS (128KB) only for the final 8-way cross-wave K reduction.

typedef __bf16 bf16x8 __attribute__((ext_vector_type(8)));
typedef float f32x16 __attribute__((ext_vector_type(16)));

#define SCALE_Q 0.14907119849998599f  // 1/sqrt(45)

__device__ __constant__ int g_pairP[45] = {
  0,0,0,0,0,0,0,0,0, 1,1,1,1,1,1,1,1, 2,2,2,2,2,2,2,
  3,3,3,3,3,3, 4,4,4,4,4, 5,5,5,5, 6,6,6, 7,7, 8};
__device__ __constant__ int g_pairQ[45] = {
  0,1,2,3,4,5,6,7,8, 1,2,3,4,5,6,7,8, 2,3,4,5,6,7,8,
  3,4,5,6,7,8, 4,5,6,7,8, 5,6,7,8, 6,7,8, 7,8, 8};

constexpr int cP[45] = {
  0,0,0,0,0,0,0,0,0, 1,1,1,1,1,1,1,1, 2,2,2,2,2,2,2,
  3,3,3,3,3,3, 4,4,4,4,4, 5,5,5,5, 6,6,6, 7,7, 8};
constexpr int cQ[45] = {
  0,1,2,3,4,5,6,7,8, 1,2,3,4,5,6,7,8, 2,3,4,5,6,7,8,
  3,4,5,6,7,8, 4,5,6,7,8, 5,6,7,8, 6,7,8, 7,8, 8};

union AFrag { unsigned int u[4]; bf16x8 v; };
union BFrag { uint4 q; bf16x8 v; };

__device__ inline unsigned int pack_bf16x2(float a, float b){
  union { __hip_bfloat16 h; unsigned short s; } ca, cb;
  ca.h = __float2bfloat16(a);
  cb.h = __float2bfloat16(b);
  return (unsigned int)ca.s | ((unsigned int)cb.s << 16);
}

template<int F>
__device__ inline float slotval(const float (&xp)[9]){
  if constexpr (F < 9)       return xp[F];
  else if constexpr (F < 54) return xp[cP[F - 9]] * xp[cQ[F - 9]];
  else                       return 0.0f;
}

// A-frags for k-half KH: frag element e of kstep ks = feature slot ks*16 + KH*8 + e.
template<int KH>
__device__ inline void build_afrag(const float (&xp)[9], AFrag (&a)[4]){
  #pragma unroll
  for (int ks = 0; ks < 4; ++ks){
    #pragma unroll
    for (int j = 0; j < 4; ++j){
      const int f0c = ks * 16 + KH * 8 + 2 * j;   // compile-time after unroll
      float v0, v1;
      switch (f0c) {
        default: v0 = 0.f; v1 = 0.f; break;
  #define CASE(F) case F: v0 = slotval<F>(xp); v1 = slotval<F+1>(xp); break;
        CASE(0) CASE(2) CASE(4) CASE(6) CASE(8) CASE(10) CASE(12) CASE(14)
        CASE(16) CASE(18) CASE(20) CASE(22) CASE(24) CASE(26) CASE(28) CASE(30)
        CASE(32) CASE(34) CASE(36) CASE(38) CASE(40) CASE(42) CASE(44) CASE(46)
        CASE(48) CASE(50) CASE(52) CASE(54) CASE(56) CASE(58) CASE(60) CASE(62)
  #undef CASE
      }
      a[ks].u[j] = pack_bf16x2(v0, v1);
    }
  }
}

// ---------------- prep: pack weights into MFMA B-fragment order ----------------
// chunk g: c=g>>9; inner=g&511=(ks*2+nb)*64+lane;
// chunk (8 bf16) = B[k-slot = ks*16+(lane>>5)*8+j][n = nb*32+(lane&31)]
__global__ __launch_bounds__(256) void volt_pack(const float* __restrict__ W1,
                                                 const float* __restrict__ W2,
                                                 __hip_bfloat16* __restrict__ Bpack){
  int g = blockIdx.x * 256 + threadIdx.x;      // 0..32767
  int c     = g >> 9;
  int inner = g & 511;
  int lane  = inner & 63;
  int ks    = inner >> 7;
  int nb    = (inner >> 6) & 1;
  int n     = nb * 32 + (lane & 31);
  int kh    = lane >> 5;
  #pragma unroll
  for (int j = 0; j < 8; ++j){
    int f = ks * 16 + kh * 8 + j;
    float wv = 0.0f;
    if (f < 9)       wv = W1[(c * 9 + f) * 64 + n];
    else if (f < 54){
      int t = f - 9;
      wv = SCALE_Q * W2[(c * 81 + g_pairP[t] * 9 + g_pairQ[t]) * 64 + n];
    }
    Bpack[(size_t)g * 8 + j] = __float2bfloat16(wv);
  }
}

// ---------------- main fused kernel ----------------
__global__ __launch_bounds__(512, 2) void volt_main(const float* __restrict__ x,
                                                    const uint4* __restrict__ Bpack,
                                                    const float* __restrict__ bias_w,
                                                    float* __restrict__ out){
  __shared__ float red[8 * 4096];              // 128 KB: per-wave partial 64x64 tiles
  const int tid  = threadIdx.x;
  const int lane = tid & 63;
  const int kv   = tid >> 6;                   // wave 0..7, channels kv*8..kv*8+7
  const int b    = blockIdx.x >> 6;
  const int h0   = blockIdx.x & 63;

  const int p  = lane & 31;                    // pixel within sub-tile
  const int kh = lane >> 5;                    // k-half

  const int hm = (h0 > 0)  ? h0 - 1 : 0;
  const int hp = (h0 < 63) ? h0 + 1 : 63;

  const float* xw   = x + ((size_t)(b * 64 + kv * 8)) * 4096;
  const uint4* bsrc = Bpack + (size_t)(kv * 8) * 512 + lane;

  // full-row loader: lane holds column `lane` of rows h0-1, h0, h0+1 (row-clamped)
  auto loadX = [&](int i, float (&v)[3]){
    const float* xc = xw + (size_t)i * 4096;
    v[0] = xc[hm * 64 + lane];
    v[1] = xc[h0 * 64 + lane];
    v[2] = xc[hp * 64 + lane];
    if (h0 == 0)  v[0] = 0.f;
    if (h0 == 63) v[2] = 0.f;
  };

  f32x16 acc00{}, acc01{}, acc10{}, acc11{};   // [px-tile][col-half]

  BFrag curB[8], nxtB[8];
  float cx[3], nx2[3];
  #pragma unroll
  for (int j = 0; j < 8; ++j) curB[j].q = bsrc[j * 64];
  loadX(0, cx);

  #pragma unroll
  for (int i = 0; i < 8; ++i){
    // prefetch next channel's B frags + x rows first (latency hidden by build)
    if (i < 7){
      const uint4* s = bsrc + (size_t)(i + 1) * 512;
      #pragma unroll
      for (int j = 0; j < 8; ++j) nxtB[j].q = s[j * 64];
      loadX(i + 1, nx2);
    }

    // ---- xp for both of this lane's pixels, via row shuffles ----
    // tile0 pixel p: cols p-1,p,p+1 (col -1 -> 0); tile1 pixel p+32: cols p+31..p+33 (col 64 -> 0)
    float xp0[9], xp1[9];
    #pragma unroll
    for (int dh = 0; dh < 3; ++dh){
      float hv = cx[dh];
      float l0 = __shfl(hv, p - 1);
      float m0 = __shfl(hv, p);
      float r0 = __shfl(hv, p + 1);
      float l1 = __shfl(hv, p + 31);
      float m1 = __shfl(hv, p + 32);
      float r1 = __shfl(hv, p + 33);
      xp0[dh * 3 + 0] = (p == 0)  ? 0.f : l0;
      xp0[dh * 3 + 1] = m0;
      xp0[dh * 3 + 2] = r0;
      xp1[dh * 3 + 0] = l1;
      xp1[dh * 3 + 1] = m1;
      xp1[dh * 3 + 2] = (p == 31) ? 0.f : r1;
    }

    // ---- lane-local A fragments (k-half split; complementary-mask divergence) ----
    AFrag a0[4], a1[4];
    if (kh == 0){ build_afrag<0>(xp0, a0); build_afrag<0>(xp1, a1); }
    else        { build_afrag<1>(xp0, a0); build_afrag<1>(xp1, a1); }

    // ---- MFMA: 4 ksteps x (2 px-tiles x 2 col-halves) = 4 independent chains ----
    __builtin_amdgcn_s_setprio(1);
    #pragma unroll
    for (int ks = 0; ks < 4; ++ks){
      acc00 = __builtin_amdgcn_mfma_f32_32x32x16_bf16(a0[ks].v, curB[ks*2+0].v, acc00, 0, 0, 0);
      acc01 = __builtin_amdgcn_mfma_f32_32x32x16_bf16(a0[ks].v, curB[ks*2+1].v, acc01, 0, 0, 0);
      acc10 = __builtin_amdgcn_mfma_f32_32x32x16_bf16(a1[ks].v, curB[ks*2+0].v, acc10, 0, 0, 0);
      acc11 = __builtin_amdgcn_mfma_f32_32x32x16_bf16(a1[ks].v, curB[ks*2+1].v, acc11, 0, 0, 0);
    }
    __builtin_amdgcn_s_setprio(0);

    if (i < 7){
      #pragma unroll
      for (int j = 0; j < 8; ++j) curB[j] = nxtB[j];
      cx[0] = nx2[0]; cx[1] = nx2[1]; cx[2] = nx2[2];
    }
  }

  // ---- cross-wave K reduction via LDS ----
  // C/D 32x32 layout: lane (kh,p) element r -> C[row = (r&3)+8*(r>>2)+4*kh][col = p];
  // row = pixel (within sub-tile), col = out-channel.
  {
    #pragma unroll
    for (int r = 0; r < 16; ++r){
      int rl = (r & 3) + 8 * (r >> 2) + 4 * kh;
      red[kv * 4096 + (rl)      * 64 + p     ] = acc00[r];
      red[kv * 4096 + (rl)      * 64 + p + 32] = acc01[r];
      red[kv * 4096 + (rl + 32) * 64 + p     ] = acc10[r];
      red[kv * 4096 + (rl + 32) * 64 + p + 32] = acc11[r];
    }
  }
  __syncthreads();
  const float bias = bias_w[h0];
  float* outp = out + (size_t)b * 262144 + (size_t)h0 * 4096;
  #pragma unroll
  for (int j = 0; j < 8; ++j){
    int oidx = j * 512 + tid;                  // px*64 + o, coalesced
    float v = bias;
    #pragma unroll
    for (int kvv = 0; kvv < 8; ++kvv) v += red[kvv * 4096 + oidx];
    outp[oidx] = v;
  }
}

extern "C" void kernel_launch(void* const* d_in, const int* in_sizes, int n_in,
                              void* d_out, int out_size, void* d_ws, size_t ws_size,
                              hipStream_t stream){
  const float* x      = (const float*)d_in[0];
  const float* W1     = (const float*)d_in[1];
  const float* W2     = (const float*)d_in[2];
  const float* bias_w = (const float*)d_in[3];
  float* out = (float*)d_out;
  __hip_bfloat16* Bpack = (__hip_bfloat16*)d_ws;   // 512 KB

  volt_pack<<<128, 256, 0, stream>>>(W1, W2, Bpack);
  volt_main<<<256, 512, 0, stream>>>(x, (const uint4*)d_ws, bias_w, out);
}

// Round 7
// 24.263 us; speedup vs baseline: 1.2787x; 1.0949x over previous
//
#include <hip/hip_runtime.h>
#include <hip/hip_bf16.h>

// Volterra conv (K=3, orders 1+2) as one fused bf16 MFMA GEMM:
// out[b, l, o] = sum_{c,f} A[l, c*64+f] * Wc[c*64+f, o]
//   f<9: linear xp[f]; 9<=f<54: xp[P]*xp[Q]/sqrt(45) (scale folded into Bpack); f>=54: 0
// Flat out = b*262144 + h_pix*4096 + w_pix*64 + o; bias = bias_w[h_pix] (zeros).
//
// r7 = r4 structure (proven best: 22.7 us) with ONE change: the channel loop is a
// genuine #pragma unroll 1 loop (4 iters x 2 channels, named ping-pong buffers) so
// the loop body (~3-4 KB) stays I$-resident instead of streaming ~30+ KB of fully
// unrolled code through the front-end once. Theory: all r2-r6 variants were
// front-end (I$ miss) bound -- every pipe idle, time invariant to structure.

typedef __bf16 bf16x8 __attribute__((ext_vector_type(8)));
typedef float f32x16 __attribute__((ext_vector_type(16)));

#define SCALE_Q 0.14907119849998599f  // 1/sqrt(45)

__device__ __constant__ int g_pairP[45] = {
  0,0,0,0,0,0,0,0,0, 1,1,1,1,1,1,1,1, 2,2,2,2,2,2,2,
  3,3,3,3,3,3, 4,4,4,4,4, 5,5,5,5, 6,6,6, 7,7, 8};
__device__ __constant__ int g_pairQ[45] = {
  0,1,2,3,4,5,6,7,8, 1,2,3,4,5,6,7,8, 2,3,4,5,6,7,8,
  3,4,5,6,7,8, 4,5,6,7,8, 5,6,7,8, 6,7,8, 7,8, 8};

union AFrag { unsigned int u[4]; bf16x8 v; };
union BFrag { uint4 q; bf16x8 v; };

__device__ inline unsigned int pack_bf16x2(float a, float b){
  union { __hip_bfloat16 h; unsigned short s; } ca, cb;
  ca.h = __float2bfloat16(a);
  cb.h = __float2bfloat16(b);
  return (unsigned int)ca.s | ((unsigned int)cb.s << 16);
}

// half-exchange: U = own k-low dword, V = own k-high dword ->
// o0 = frag word for output rows 0..31, o1 = for rows 32..63.
__device__ inline void half_swap(unsigned int U, unsigned int V,
                                 unsigned int& o0, unsigned int& o1, int lane){
#if __has_builtin(__builtin_amdgcn_permlane32_swap)
  auto rr = __builtin_amdgcn_permlane32_swap(U, V, false, false);
  o0 = rr[0]; o1 = rr[1];
#else
  unsigned int Ux = (unsigned int)__shfl_xor((int)U, 32);
  unsigned int Vx = (unsigned int)__shfl_xor((int)V, 32);
  const bool hi = (lane >= 32);
  o0 = hi ? Vx : U;
  o1 = hi ? V : Ux;
#endif
}

// ---------------- prep: pack weights into MFMA B-fragment order ----------------
// chunk g: c=g>>9; inner=g&511=(ks*2+nb)*64+lane;
// chunk (8 bf16) = B[k-slot = ks*16+(lane>>5)*8+j][n = nb*32+(lane&31)]
__global__ __launch_bounds__(256) void volt_pack(const float* __restrict__ W1,
                                                 const float* __restrict__ W2,
                                                 __hip_bfloat16* __restrict__ Bpack){
  int g = blockIdx.x * 256 + threadIdx.x;      // 0..32767
  int c     = g >> 9;
  int inner = g & 511;
  int lane  = inner & 63;
  int ks    = inner >> 7;
  int nb    = (inner >> 6) & 1;
  int n     = nb * 32 + (lane & 31);
  int kh    = lane >> 5;
  #pragma unroll
  for (int j = 0; j < 8; ++j){
    int f = ks * 16 + kh * 8 + j;
    float wv = 0.0f;
    if (f < 9)       wv = W1[(c * 9 + f) * 64 + n];
    else if (f < 54){
      int t = f - 9;
      wv = SCALE_Q * W2[(c * 81 + g_pairP[t] * 9 + g_pairQ[t]) * 64 + n];
    }
    Bpack[(size_t)g * 8 + j] = __float2bfloat16(wv);
  }
}

// ---------------- main fused kernel ----------------
__global__ __launch_bounds__(512, 2) void volt_main(const float* __restrict__ x,
                                                    const uint4* __restrict__ Bpack,
                                                    const float* __restrict__ bias_w,
                                                    float* __restrict__ out){
  __shared__ float red[8 * 4096];              // 128 KB: per-wave partial 64x64 tiles
  const int tid  = threadIdx.x;
  const int lane = tid & 63;
  const int kv   = tid >> 6;                   // wave 0..7, channels kv*8..kv*8+7
  const int b    = blockIdx.x >> 6;
  const int h0   = blockIdx.x & 63;

  const int hm = (h0 > 0)  ? h0 - 1 : 0;       // clamped; masked in build
  const int hp = (h0 < 63) ? h0 + 1 : 63;
  const float* xw   = x + ((size_t)(b * 64 + kv * 8)) * 4096;
  const uint4* bsrc = Bpack + (size_t)(kv * 8) * 512 + lane;

  constexpr int kP[45] = {
    0,0,0,0,0,0,0,0,0, 1,1,1,1,1,1,1,1, 2,2,2,2,2,2,2,
    3,3,3,3,3,3, 4,4,4,4,4, 5,5,5,5, 6,6,6, 7,7, 8};
  constexpr int kQ[45] = {
    0,1,2,3,4,5,6,7,8, 1,2,3,4,5,6,7,8, 2,3,4,5,6,7,8,
    3,4,5,6,7,8, 4,5,6,7,8, 5,6,7,8, 6,7,8, 7,8, 8};

  f32x16 acc00{}, acc01{}, acc10{}, acc11{};   // [row-half][col-half]

  auto loadB = [&](int i, BFrag (&B)[8]){
    const uint4* s = bsrc + (size_t)i * 512;
    #pragma unroll
    for (int j = 0; j < 8; ++j) B[j].q = s[j * 64];
  };
  auto loadX = [&](int i, float (&v)[3]){
    const float* xc = xw + (size_t)i * 4096;
    v[0] = xc[hm * 64 + lane];
    v[1] = xc[h0 * 64 + lane];
    v[2] = xc[hp * 64 + lane];
  };

  // one channel's feature-build + 16 MFMAs (statically indexed throughout)
  auto compute = [&](const float (&cx)[3], const BFrag (&Bf)[8]){
    float xp[9];
    #pragma unroll
    for (int dh = 0; dh < 3; ++dh){
      float mid = cx[dh];
      if (dh == 0 && h0 == 0)  mid = 0.f;      // wave-uniform row clamp
      if (dh == 2 && h0 == 63) mid = 0.f;
      float lf = __shfl(mid, lane - 1);
      float rt = __shfl(mid, lane + 1);
      xp[dh * 3 + 0] = (lane == 0)  ? 0.f : lf;
      xp[dh * 3 + 1] = mid;
      xp[dh * 3 + 2] = (lane == 63) ? 0.f : rt;
    }
    float pr[45];
    #pragma unroll
    for (int t = 0; t < 45; ++t) pr[t] = xp[kP[t]] * xp[kQ[t]];

    unsigned int d[32];                        // 64 bf16 feature slots as dwords
    #pragma unroll
    for (int s = 0; s < 32; ++s){
      const int f0 = 2 * s, f1 = 2 * s + 1;
      float a  = (f0 < 9) ? xp[f0] : ((f0 < 54) ? pr[f0 - 9] : 0.0f);
      float b2 = (f1 < 9) ? xp[f1] : ((f1 < 54) ? pr[f1 - 9] : 0.0f);
      d[s] = pack_bf16x2(a, b2);
    }

    AFrag a0[4], a1[4];
    #pragma unroll
    for (int ks = 0; ks < 4; ++ks){
      #pragma unroll
      for (int j = 0; j < 4; ++j){
        half_swap(d[ks * 8 + j], d[ks * 8 + 4 + j], a0[ks].u[j], a1[ks].u[j], lane);
      }
    }

    __builtin_amdgcn_s_setprio(1);
    #pragma unroll
    for (int ks = 0; ks < 4; ++ks){
      acc00 = __builtin_amdgcn_mfma_f32_32x32x16_bf16(a0[ks].v, Bf[ks*2+0].v, acc00, 0, 0, 0);
      acc01 = __builtin_amdgcn_mfma_f32_32x32x16_bf16(a0[ks].v, Bf[ks*2+1].v, acc01, 0, 0, 0);
      acc10 = __builtin_amdgcn_mfma_f32_32x32x16_bf16(a1[ks].v, Bf[ks*2+0].v, acc10, 0, 0, 0);
      acc11 = __builtin_amdgcn_mfma_f32_32x32x16_bf16(a1[ks].v, Bf[ks*2+1].v, acc11, 0, 0, 0);
    }
    __builtin_amdgcn_s_setprio(0);
  };

  // ---- ping-pong channel loop: REAL loop (I$-resident body), 2 channels/iter ----
  BFrag bufA[8], bufB[8];
  float cxA[3], cxB[3];
  loadB(0, bufA); loadX(0, cxA);

  #pragma unroll 1
  for (int ii = 0; ii < 4; ++ii){
    const int i0 = ii * 2;
    loadB(i0 + 1, bufB); loadX(i0 + 1, cxB);   // prefetch odd channel
    compute(cxA, bufA);                        // compute even channel
    if (ii < 3){ loadB(i0 + 2, bufA); loadX(i0 + 2, cxA); }  // prefetch next even
    compute(cxB, bufB);                        // compute odd channel
  }

  // ---- cross-wave K reduction via LDS ----
  {
    const int colbase = lane & 31;
    const int rowadd  = 4 * (lane >> 5);
    #pragma unroll
    for (int r = 0; r < 16; ++r){
      int rl = (r & 3) + 8 * (r >> 2) + rowadd;              // 32x32 C/D layout
      red[kv * 4096 + (rl)      * 64 + colbase     ] = acc00[r];
      red[kv * 4096 + (rl)      * 64 + colbase + 32] = acc01[r];
      red[kv * 4096 + (rl + 32) * 64 + colbase     ] = acc10[r];
      red[kv * 4096 + (rl + 32) * 64 + colbase + 32] = acc11[r];
    }
  }
  __syncthreads();
  const float bias = bias_w[h0];
  float* outp = out + (size_t)b * 262144 + (size_t)h0 * 4096;
  #pragma unroll
  for (int j = 0; j < 8; ++j){
    int oidx = j * 512 + tid;                  // px*64 + o, coalesced
    float v = bias;
    #pragma unroll
    for (int kvv = 0; kvv < 8; ++kvv) v += red[kvv * 4096 + oidx];
    outp[oidx] = v;
  }
}

extern "C" void kernel_launch(void* const* d_in, const int* in_sizes, int n_in,
                              void* d_out, int out_size, void* d_ws, size_t ws_size,
                              hipStream_t stream){
  const float* x      = (const float*)d_in[0];
  const float* W1     = (const float*)d_in[1];
  const float* W2     = (const float*)d_in[2];
  const float* bias_w = (const float*)d_in[3];
  float* out = (float*)d_out;
  __hip_bfloat16* Bpack = (__hip_bfloat16*)d_ws;   // 512 KB

  volt_pack<<<128, 256, 0, stream>>>(W1, W2, Bpack);
  volt_main<<<256, 512, 0, stream>>>(x, (const uint4*)d_ws, bias_w, out);
}